// Round 3
// baseline (14511.014 us; speedup 1.0000x reference)
//
#include <hip/hip_runtime.h>
#include <stdint.h>

// ---------------------------------------------------------------------------
// 2-layer LSTM (T=256, B=256, F=128, H=1024) for MI355X (gfx950).
// Runtime-adaptive workspace (CHUNK in {64,32,16,8,4}); diag path writes
// 1e6+ws_MB into y if even the smallest layout doesn't fit.
//   chunk loop: lstm_layer0 (fused x-proj, W resident in VGPRs, grid barrier
//   per step, rolling (CH+1)-slot out0 slab) -> gemm xw1 -> lstm_layer1.
// ---------------------------------------------------------------------------

typedef __bf16 bf16x8 __attribute__((ext_vector_type(8)));
typedef float  f32x4  __attribute__((ext_vector_type(4)));
typedef unsigned short ushort8v __attribute__((ext_vector_type(8)));
typedef unsigned short ushort4v __attribute__((ext_vector_type(4)));
typedef unsigned int   uint4v   __attribute__((ext_vector_type(4)));

#define T_STEPS 256
#define BATCH   256
#define HDIM    1024
#define GDIM    4096
#define FDIM    128

static __device__ __forceinline__ float bf2f(unsigned short u) {
  union { unsigned int i; float f; } v; v.i = ((unsigned int)u) << 16; return v.f;
}
static __device__ __forceinline__ unsigned short f2bf(float f) {
  return __builtin_bit_cast(unsigned short, (__bf16)f);
}
static __device__ __forceinline__ float sigm(float x) { return 1.f / (1.f + __expf(-x)); }
static __device__ __forceinline__ float tanh_f(float x) { return 2.f / (1.f + __expf(-2.f * x)) - 1.f; }

__global__ void conv_bf16(const float* __restrict__ s, unsigned short* __restrict__ d, int n) {
  int i = blockIdx.x * 256 + threadIdx.x;
  if (i < n) d[i] = f2bf(s[i]);
}

__global__ void diag_kernel(float* out, int n, float v) {
  int i = blockIdx.x * 256 + threadIdx.x;
  if (i < n) out[i] = v;
}

// device-scope grid barrier; bounded spin (~7ms worst) so a residency failure
// gives a wrong answer, never a hang/abort.
__device__ __forceinline__ void grid_barrier(unsigned int* bar, unsigned int nwg) {
  __syncthreads();
  if (threadIdx.x == 0) {
    __threadfence();
    unsigned int g0 = __hip_atomic_load(&bar[1], __ATOMIC_RELAXED, __HIP_MEMORY_SCOPE_AGENT);
    unsigned int my = __hip_atomic_fetch_add(&bar[0], 1u, __ATOMIC_ACQ_REL, __HIP_MEMORY_SCOPE_AGENT);
    if (my == nwg - 1u) {
      __hip_atomic_store(&bar[0], 0u, __ATOMIC_RELAXED, __HIP_MEMORY_SCOPE_AGENT);
      __hip_atomic_fetch_add(&bar[1], 1u, __ATOMIC_RELEASE, __HIP_MEMORY_SCOPE_AGENT);
    } else {
      for (unsigned int it = 0; it < (1u << 16); ++it) {
        if (__hip_atomic_load(&bar[1], __ATOMIC_ACQUIRE, __HIP_MEMORY_SCOPE_AGENT) != g0) break;
        __builtin_amdgcn_s_sleep(1);
      }
    }
  }
  __syncthreads();
}

// --------------------------- gemm_bt: C = A @ B^T ---------------------------
// A: (M,K) bf16 row-major. B: (4096,K) bf16. Plain vectorized LDS staging
// (no global_load_lds this round - minimizing fault surface).
// Output alt layout xw[(t_local*4096 + n)*256 + b], m = t_local*256 + b.
__global__ __launch_bounds__(256) void gemm_bt_xw(
    const unsigned short* __restrict__ A,
    const unsigned short* __restrict__ B,
    unsigned short* __restrict__ xw,
    int K)
{
  const int tid = threadIdx.x, lane = tid & 63, w = tid >> 6;
  const int m0 = blockIdx.x * 128;
  const int n0 = blockIdx.y * 128;
  __shared__ unsigned short As[128 * 64];
  __shared__ unsigned short Bs[128 * 64];
  const int mrow0 = (w & 1) * 64, ncol0 = (w >> 1) * 64;
  const int quad = lane >> 4;

  f32x4 acc[4][4];
  #pragma unroll
  for (int i = 0; i < 4; ++i)
    #pragma unroll
    for (int j = 0; j < 4; ++j) acc[i][j] = f32x4{0.f, 0.f, 0.f, 0.f};

  const int kiter = K >> 6;
  for (int ki = 0; ki < kiter; ++ki) {
    const int k0 = ki * 64;
    __syncthreads();
    #pragma unroll
    for (int i = 0; i < 4; ++i) {
      int G = i * 256 + tid;              // granule 0..1023
      int row = G >> 3, c8 = (G & 7) * 8; // 8 granules of 8 elems per 64-col row
      uint4v va = *(const uint4v*)(A + (size_t)(m0 + row) * K + k0 + c8);
      uint4v vb = *(const uint4v*)(B + (size_t)(n0 + row) * K + k0 + c8);
      *(uint4v*)(As + row * 64 + c8) = va;
      *(uint4v*)(Bs + row * 64 + c8) = vb;
    }
    __syncthreads();
    #pragma unroll
    for (int kk = 0; kk < 2; ++kk) {
      bf16x8 af[4], bfr[4];
      #pragma unroll
      for (int mt = 0; mt < 4; ++mt)
        af[mt] = *(const bf16x8*)(As + (mrow0 + mt * 16 + (lane & 15)) * 64 + kk * 32 + quad * 8);
      #pragma unroll
      for (int nt = 0; nt < 4; ++nt)
        bfr[nt] = *(const bf16x8*)(Bs + (ncol0 + nt * 16 + (lane & 15)) * 64 + kk * 32 + quad * 8);
      #pragma unroll
      for (int mt = 0; mt < 4; ++mt)
        #pragma unroll
        for (int nt = 0; nt < 4; ++nt)
          acc[mt][nt] = __builtin_amdgcn_mfma_f32_16x16x32_bf16(af[mt], bfr[nt], acc[mt][nt], 0, 0, 0);
    }
  }
  #pragma unroll
  for (int mt = 0; mt < 4; ++mt) {
    int m = m0 + mrow0 + mt * 16 + quad * 4;
    int tl = m >> 8, b = m & 255;
    #pragma unroll
    for (int nt = 0; nt < 4; ++nt) {
      int col = n0 + ncol0 + nt * 16 + (lane & 15);
      ushort4v v;
      v.x = f2bf(acc[mt][nt][0]); v.y = f2bf(acc[mt][nt][1]);
      v.z = f2bf(acc[mt][nt][2]); v.w = f2bf(acc[mt][nt][3]);
      *(ushort4v*)(xw + ((size_t)tl * GDIM + col) * BATCH + b) = v;
    }
  }
}

// --------------------------- layer 0: fused persistent chunk -----------------
// 256 WGs x 256 thr, 1/CU. WG (mi=wg&7, ni=wg>>3): rows [32mi,+32), cols [32ni,+32).
// Wave g = gate g. W_hh0 tile (256 VGPR) + W_ih0 tile (32 VGPR) resident.
// Rolling out0 slab: read h from slot (t-t0), write to slot (t-t0+1);
// last step also writes slot 0 (next chunk's h_{t0-1}).
__global__ __launch_bounds__(256, 1) void lstm_layer0_kernel(
    const unsigned short* __restrict__ xbf,  // (T,B,F) bf16
    const float* __restrict__ Wih,           // (4096,128) fp32
    const float* __restrict__ Whh,           // (4096,1024) fp32
    const float* __restrict__ bih,
    const float* __restrict__ bhh,
    unsigned short* __restrict__ slab,       // (ch_len+1, B, H) bf16
    float* __restrict__ cstate,              // (B,H) fp32
    int t0, int ch_len,
    float* __restrict__ dout_h,
    float* __restrict__ dout_c,
    unsigned int* __restrict__ bar)
{
  const int tid = threadIdx.x, lane = tid & 63, wv = tid >> 6;
  const int quad = lane >> 4;
  const int wg = blockIdx.x;
  const int mi = wg & 7, ni = wg >> 3;
  const int r0 = mi * 32, hc0 = ni * 32;

  __shared__ unsigned short As[32 * 1040];
  __shared__ float gbuf[4][32][36];

  // W_hh fragments -> VGPRs
  bf16x8 whh[2][32];
  #pragma unroll
  for (int nt = 0; nt < 2; ++nt) {
    const float* wrow = Whh + (size_t)(wv * HDIM + hc0 + nt * 16 + (lane & 15)) * HDIM + quad * 8;
    #pragma unroll
    for (int kk = 0; kk < 32; ++kk) {
      f32x4 f0 = *(const f32x4*)(wrow + kk * 32);
      f32x4 f1 = *(const f32x4*)(wrow + kk * 32 + 4);
      bf16x8 r;
      r[0] = (__bf16)f0[0]; r[1] = (__bf16)f0[1]; r[2] = (__bf16)f0[2]; r[3] = (__bf16)f0[3];
      r[4] = (__bf16)f1[0]; r[5] = (__bf16)f1[1]; r[6] = (__bf16)f1[2]; r[7] = (__bf16)f1[3];
      whh[nt][kk] = r;
    }
  }
  // W_ih fragments (K=128) -> VGPRs
  bf16x8 wih[2][4];
  #pragma unroll
  for (int nt = 0; nt < 2; ++nt) {
    const float* wrow = Wih + (size_t)(wv * HDIM + hc0 + nt * 16 + (lane & 15)) * FDIM + quad * 8;
    #pragma unroll
    for (int kk = 0; kk < 4; ++kk) {
      f32x4 f0 = *(const f32x4*)(wrow + kk * 32);
      f32x4 f1 = *(const f32x4*)(wrow + kk * 32 + 4);
      bf16x8 r;
      r[0] = (__bf16)f0[0]; r[1] = (__bf16)f0[1]; r[2] = (__bf16)f0[2]; r[3] = (__bf16)f0[3];
      r[4] = (__bf16)f1[0]; r[5] = (__bf16)f1[1]; r[6] = (__bf16)f1[2]; r[7] = (__bf16)f1[3];
      wih[nt][kk] = r;
    }
  }

  const int hcl = tid & 31, rg = tid >> 5;
  float bias[4];
  #pragma unroll
  for (int g = 0; g < 4; ++g)
    bias[g] = bih[g * HDIM + hc0 + hcl] + bhh[g * HDIM + hc0 + hcl];

  float c[4];
  #pragma unroll
  for (int r = 0; r < 4; ++r)
    c[r] = (t0 == 0) ? 0.f : cstate[(size_t)(r0 + rg * 4 + r) * HDIM + hc0 + hcl];

  const int tend = t0 + ch_len;
  #pragma unroll 1
  for (int t = t0; t < tend; ++t) {
    f32x4 acc[2][2];
    #pragma unroll
    for (int mt = 0; mt < 2; ++mt)
      #pragma unroll
      for (int nt = 0; nt < 2; ++nt) acc[mt][nt] = f32x4{0.f, 0.f, 0.f, 0.f};

    // x projection (K=128), fragments straight from global
    #pragma unroll
    for (int j = 0; j < 4; ++j) {
      bf16x8 af[2];
      #pragma unroll
      for (int mt = 0; mt < 2; ++mt)
        af[mt] = *(const bf16x8*)(xbf + (size_t)(t * BATCH + r0 + mt * 16 + (lane & 15)) * FDIM + j * 32 + quad * 8);
      #pragma unroll
      for (int mt = 0; mt < 2; ++mt)
        #pragma unroll
        for (int nt = 0; nt < 2; ++nt)
          acc[mt][nt] = __builtin_amdgcn_mfma_f32_16x16x32_bf16(af[mt], wih[nt][j], acc[mt][nt], 0, 0, 0);
    }

    if (t > 0) {
      const unsigned short* Aprev = slab + (size_t)(t - t0) * (BATCH * HDIM);
      #pragma unroll
      for (int p = 0; p < 16; ++p) {
        int idx = p * 256 + tid;
        int row = idx >> 7, gc = idx & 127;
        *(uint4v*)((char*)As + row * 2080 + gc * 16) =
            *(const uint4v*)(Aprev + (size_t)(r0 + row) * HDIM + gc * 8);
      }
      __syncthreads();
      #pragma unroll
      for (int j = 0; j < 32; ++j) {
        bf16x8 af[2];
        #pragma unroll
        for (int mt = 0; mt < 2; ++mt)
          af[mt] = *(const bf16x8*)((const char*)As + (mt * 16 + (lane & 15)) * 2080 + j * 64 + quad * 16);
        #pragma unroll
        for (int mt = 0; mt < 2; ++mt)
          #pragma unroll
          for (int nt = 0; nt < 2; ++nt)
            acc[mt][nt] = __builtin_amdgcn_mfma_f32_16x16x32_bf16(af[mt], whh[nt][j], acc[mt][nt], 0, 0, 0);
      }
    }

    __syncthreads();
    #pragma unroll
    for (int mt = 0; mt < 2; ++mt)
      #pragma unroll
      for (int nt = 0; nt < 2; ++nt) {
        int hl = nt * 16 + (lane & 15);
        int rq = mt * 16 + quad * 4;
        *(f32x4*)&gbuf[wv][hl][rq] = acc[mt][nt];
      }
    __syncthreads();

    unsigned short* hdst = slab + (size_t)(t - t0 + 1) * (BATCH * HDIM);
    unsigned short* hdst0 = slab;  // slot 0, written on last step for next chunk
    #pragma unroll
    for (int r = 0; r < 4; ++r) {
      int row = rg * 4 + r;
      float gi = gbuf[0][hcl][row] + bias[0];
      float gf = gbuf[1][hcl][row] + bias[1];
      float gg = gbuf[2][hcl][row] + bias[2];
      float go = gbuf[3][hcl][row] + bias[3];
      float iv = sigm(gi), fv = sigm(gf), gv = tanh_f(gg), ov = sigm(go);
      float cn = fv * c[r] + iv * gv;
      c[r] = cn;
      float hv = ov * tanh_f(cn);
      int gidx = (r0 + row) * HDIM + hc0 + hcl;
      unsigned short hb = f2bf(hv);
      hdst[gidx] = hb;
      if (t == tend - 1) { hdst0[gidx] = hb; cstate[gidx] = cn; }
      if (t == T_STEPS - 1) { dout_h[gidx] = hv; dout_c[gidx] = cn; }
    }

    if (t != tend - 1) grid_barrier(bar, gridDim.x);
  }
}

// --------------------------- layer 1: persistent chunk ----------------------
__global__ __launch_bounds__(256, 1) void lstm_layer1_kernel(
    const unsigned short* __restrict__ xw,   // (ch_len, 4096, 256) bf16
    const float* __restrict__ Whh,
    const float* __restrict__ bih,
    const float* __restrict__ bhh,
    unsigned short* __restrict__ hpp,        // 2-slot ping-pong
    float* __restrict__ cstate,
    int t0, int ch_len,
    unsigned short* __restrict__ h1t0,
    float* __restrict__ dout_h,
    float* __restrict__ dout_c,
    unsigned int* __restrict__ bar)
{
  const int tid = threadIdx.x, lane = tid & 63, wv = tid >> 6;
  const int quad = lane >> 4;
  const int wg = blockIdx.x;
  const int mi = wg & 7, ni = wg >> 3;
  const int r0 = mi * 32, hc0 = ni * 32;

  __shared__ unsigned short As[32 * 1040];
  __shared__ float gbuf[4][32][36];

  bf16x8 whh[2][32];
  #pragma unroll
  for (int nt = 0; nt < 2; ++nt) {
    const float* wrow = Whh + (size_t)(wv * HDIM + hc0 + nt * 16 + (lane & 15)) * HDIM + quad * 8;
    #pragma unroll
    for (int kk = 0; kk < 32; ++kk) {
      f32x4 f0 = *(const f32x4*)(wrow + kk * 32);
      f32x4 f1 = *(const f32x4*)(wrow + kk * 32 + 4);
      bf16x8 r;
      r[0] = (__bf16)f0[0]; r[1] = (__bf16)f0[1]; r[2] = (__bf16)f0[2]; r[3] = (__bf16)f0[3];
      r[4] = (__bf16)f1[0]; r[5] = (__bf16)f1[1]; r[6] = (__bf16)f1[2]; r[7] = (__bf16)f1[3];
      whh[nt][kk] = r;
    }
  }

  const int hcl = tid & 31, rg = tid >> 5;
  float bias[4];
  #pragma unroll
  for (int g = 0; g < 4; ++g)
    bias[g] = bih[g * HDIM + hc0 + hcl] + bhh[g * HDIM + hc0 + hcl];

  float c[4];
  #pragma unroll
  for (int r = 0; r < 4; ++r)
    c[r] = (t0 == 0) ? 0.f : cstate[(size_t)(r0 + rg * 4 + r) * HDIM + hc0 + hcl];

  const int tend = t0 + ch_len;
  #pragma unroll 1
  for (int t = t0; t < tend; ++t) {
    f32x4 acc[2][2];
    #pragma unroll
    for (int mt = 0; mt < 2; ++mt)
      #pragma unroll
      for (int nt = 0; nt < 2; ++nt) acc[mt][nt] = f32x4{0.f, 0.f, 0.f, 0.f};

    if (t > 0) {
      const unsigned short* Aprev = hpp + (size_t)((t - 1) & 1) * (BATCH * HDIM);
      #pragma unroll
      for (int p = 0; p < 16; ++p) {
        int idx = p * 256 + tid;
        int row = idx >> 7, gc = idx & 127;
        *(uint4v*)((char*)As + row * 2080 + gc * 16) =
            *(const uint4v*)(Aprev + (size_t)(r0 + row) * HDIM + gc * 8);
      }
      __syncthreads();
      #pragma unroll
      for (int j = 0; j < 32; ++j) {
        bf16x8 af[2];
        #pragma unroll
        for (int mt = 0; mt < 2; ++mt)
          af[mt] = *(const bf16x8*)((const char*)As + (mt * 16 + (lane & 15)) * 2080 + j * 64 + quad * 16);
        #pragma unroll
        for (int mt = 0; mt < 2; ++mt)
          #pragma unroll
          for (int nt = 0; nt < 2; ++nt)
            acc[mt][nt] = __builtin_amdgcn_mfma_f32_16x16x32_bf16(af[mt], whh[nt][j], acc[mt][nt], 0, 0, 0);
      }
    }

    __syncthreads();
    #pragma unroll
    for (int mt = 0; mt < 2; ++mt)
      #pragma unroll
      for (int nt = 0; nt < 2; ++nt) {
        int hl = nt * 16 + (lane & 15);
        int rq = mt * 16 + quad * 4;
        *(f32x4*)&gbuf[wv][hl][rq] = acc[mt][nt];
      }
    __syncthreads();

    float xwv[4][4];
    #pragma unroll
    for (int g = 0; g < 4; ++g) {
      const unsigned short* xp =
          xw + ((size_t)(t - t0) * GDIM + g * HDIM + hc0 + hcl) * BATCH + r0 + rg * 4;
      ushort4v u = *(const ushort4v*)xp;
      xwv[g][0] = bf2f(u.x); xwv[g][1] = bf2f(u.y);
      xwv[g][2] = bf2f(u.z); xwv[g][3] = bf2f(u.w);
    }
    unsigned short* hdst = hpp + (size_t)(t & 1) * (BATCH * HDIM);
    #pragma unroll
    for (int r = 0; r < 4; ++r) {
      int row = rg * 4 + r;
      float gi = gbuf[0][hcl][row] + xwv[0][r] + bias[0];
      float gf = gbuf[1][hcl][row] + xwv[1][r] + bias[1];
      float gg = gbuf[2][hcl][row] + xwv[2][r] + bias[2];
      float go = gbuf[3][hcl][row] + xwv[3][r] + bias[3];
      float iv = sigm(gi), fv = sigm(gf), gv = tanh_f(gg), ov = sigm(go);
      float cn = fv * c[r] + iv * gv;
      c[r] = cn;
      float hv = ov * tanh_f(cn);
      int gidx = (r0 + row) * HDIM + hc0 + hcl;
      hdst[gidx] = f2bf(hv);
      if (h1t0 != nullptr && t == 0) h1t0[gidx] = f2bf(hv);
      if (t == tend - 1) cstate[gidx] = cn;
      if (t == T_STEPS - 1) { dout_h[gidx] = hv; dout_c[gidx] = cn; }
    }

    if (t != tend - 1) grid_barrier(bar, gridDim.x);
  }
}

__global__ void y_kernel(const unsigned short* __restrict__ h1t0,
                         const unsigned short* __restrict__ wlin,
                         const float* __restrict__ blin,
                         float* __restrict__ y)
{
  int b = blockIdx.x;
  int f = threadIdx.x;
  const ushort8v* hp = (const ushort8v*)(h1t0 + (size_t)b * HDIM);
  const ushort8v* wp = (const ushort8v*)(wlin + (size_t)f * HDIM);
  float acc = 0.f;
  for (int i = 0; i < HDIM / 8; ++i) {
    ushort8v hv = hp[i], wvv = wp[i];
    #pragma unroll
    for (int j = 0; j < 8; ++j) acc += bf2f(hv[j]) * bf2f(wvv[j]);
  }
  y[b * FDIM + f] = acc + blin[f];
}

// ---------------------------------------------------------------------------
extern "C" void kernel_launch(void* const* d_in, const int* in_sizes, int n_in,
                              void* d_out, int out_size, void* d_ws, size_t ws_size,
                              hipStream_t stream) {
  (void)in_sizes; (void)n_in; (void)out_size;
  const float* x    = (const float*)d_in[0];
  const float* Wih0 = (const float*)d_in[1];
  const float* Whh0 = (const float*)d_in[2];
  const float* bih0 = (const float*)d_in[3];
  const float* bhh0 = (const float*)d_in[4];
  const float* Wih1 = (const float*)d_in[5];
  const float* Whh1 = (const float*)d_in[6];
  const float* bih1 = (const float*)d_in[7];
  const float* bhh1 = (const float*)d_in[8];
  const float* Wlin = (const float*)d_in[9];
  const float* blin = (const float*)d_in[10];
  float* out = (float*)d_out;

  // fixed-size pieces (bytes)
  const size_t SZ_BAR   = 1024;
  const size_t SZ_XBF   = (size_t)T_STEPS * BATCH * FDIM * 2;   // 16 MB
  const size_t SZ_WIH1  = (size_t)GDIM * HDIM * 2;              // 8 MB
  const size_t SZ_WLIN  = (size_t)FDIM * HDIM * 2;              // 0.25 MB
  const size_t SZ_HPP   = (size_t)2 * BATCH * HDIM * 2;         // 1 MB
  const size_t SZ_H1T0  = (size_t)BATCH * HDIM * 2;             // 0.5 MB
  const size_t SZ_CST   = (size_t)BATCH * HDIM * 4;             // 1 MB each
  const size_t SLOT     = (size_t)BATCH * HDIM * 2;             // 0.5 MB
  const size_t fixed = SZ_BAR + SZ_XBF + SZ_WIH1 + SZ_WLIN + SZ_HPP + SZ_H1T0 + 2 * SZ_CST;

  // pick largest chunk that fits
  int CH = 0;
  const int cands[5] = {64, 32, 16, 8, 4};
  for (int i = 0; i < 5; ++i) {
    int c = cands[i];
    size_t need = fixed + (size_t)(c + 1) * SLOT + (size_t)c * GDIM * BATCH * 2;
    if (need <= ws_size) { CH = c; break; }
  }
  if (CH == 0) {
    // diagnostic: absmax will read ~1e6 + ws_size in MB
    float v = 1.0e6f + (float)(ws_size >> 20);
    diag_kernel<<<(32768 + 255) / 256, 256, 0, stream>>>(out, 32768, v);
    return;
  }

  char* ws = (char*)d_ws;
  size_t o = 0;
  unsigned int*   bar   = (unsigned int*)(ws + o);    o += SZ_BAR;
  unsigned short* xbf   = (unsigned short*)(ws + o);  o += SZ_XBF;
  unsigned short* wih1b = (unsigned short*)(ws + o);  o += SZ_WIH1;
  unsigned short* wlinb = (unsigned short*)(ws + o);  o += SZ_WLIN;
  unsigned short* h1pp  = (unsigned short*)(ws + o);  o += SZ_HPP;
  unsigned short* h1t0  = (unsigned short*)(ws + o);  o += SZ_H1T0;
  float*          c0st  = (float*)(ws + o);           o += SZ_CST;
  float*          c1st  = (float*)(ws + o);           o += SZ_CST;
  unsigned short* slab  = (unsigned short*)(ws + o);  o += (size_t)(CH + 1) * SLOT;
  unsigned short* xw1   = (unsigned short*)(ws + o);  o += (size_t)CH * GDIM * BATCH * 2;

  hipMemsetAsync(bar, 0, 256, stream);

  conv_bf16<<<(T_STEPS * BATCH * FDIM + 255) / 256, 256, 0, stream>>>(x, xbf, T_STEPS * BATCH * FDIM);
  conv_bf16<<<(GDIM * HDIM + 255) / 256, 256, 0, stream>>>(Wih1, wih1b, GDIM * HDIM);
  conv_bf16<<<(FDIM * HDIM + 255) / 256, 256, 0, stream>>>(Wlin, wlinb, FDIM * HDIM);

  float* hn0 = out + 32768;
  float* hn1 = out + 32768 + 262144;
  float* cn0 = out + 32768 + 524288;
  float* cn1 = out + 32768 + 524288 + 262144;

  for (int ch = 0; ch < T_STEPS / CH; ++ch) {
    int t0 = ch * CH;
    lstm_layer0_kernel<<<256, 256, 0, stream>>>(
        xbf, Wih0, Whh0, bih0, bhh0, slab, c0st, t0, CH, hn0, cn0, bar);
    gemm_bt_xw<<<dim3(CH * 2, 32), 256, 0, stream>>>(
        slab + BATCH * HDIM, wih1b, xw1, HDIM);
    lstm_layer1_kernel<<<256, 256, 0, stream>>>(
        xw1, Whh1, bih1, bhh1, h1pp, c1st, t0, CH, h1t0, hn1, cn1, bar);
  }

  y_kernel<<<256, 128, 0, stream>>>(h1t0, wlinb, blin, out);
}

// Round 4
// 8329.761 us; speedup vs baseline: 1.7421x; 1.7421x over previous
//
#include <hip/hip_runtime.h>
#include <stdint.h>

// ---------------------------------------------------------------------------
// 2-layer LSTM (T=256, B=256, F=128, H=1024) for MI355X (gfx950).
// R4: hierarchical monotonic grid barrier (separate cachelines, relaxed ops,
// one release + one acquire fence per WG per step), LDS pad fix, xw hoist.
//   chunk loop: lstm_layer0 (fused x-proj, W resident in VGPRs, grid barrier
//   per step, rolling (CH+1)-slot out0 slab) -> gemm xw1 -> lstm_layer1.
// ---------------------------------------------------------------------------

typedef __bf16 bf16x8 __attribute__((ext_vector_type(8)));
typedef float  f32x4  __attribute__((ext_vector_type(4)));
typedef unsigned short ushort8v __attribute__((ext_vector_type(8)));
typedef unsigned short ushort4v __attribute__((ext_vector_type(4)));
typedef unsigned int   uint4v   __attribute__((ext_vector_type(4)));

#define T_STEPS 256
#define BATCH   256
#define HDIM    1024
#define GDIM    4096
#define FDIM    128
#define AS_STRIDE 2064   // bytes per LDS row: 2048 + 16 pad (stride%128B==16 -> 2-way, free)

static __device__ __forceinline__ float bf2f(unsigned short u) {
  union { unsigned int i; float f; } v; v.i = ((unsigned int)u) << 16; return v.f;
}
static __device__ __forceinline__ unsigned short f2bf(float f) {
  return __builtin_bit_cast(unsigned short, (__bf16)f);
}
static __device__ __forceinline__ float sigm(float x) { return 1.f / (1.f + __expf(-x)); }
static __device__ __forceinline__ float tanh_f(float x) { return 2.f / (1.f + __expf(-2.f * x)) - 1.f; }

__global__ void conv_bf16(const float* __restrict__ s, unsigned short* __restrict__ d, int n) {
  int i = blockIdx.x * 256 + threadIdx.x;
  if (i < n) d[i] = f2bf(s[i]);
}

__global__ void diag_kernel(float* out, int n, float v) {
  int i = blockIdx.x * 256 + threadIdx.x;
  if (i < n) out[i] = v;
}

// ---------------- hierarchical monotonic grid barrier (grid == 256) ----------
// bar dword layout (memset to 0 each launch):
//   bar[64*g], g=0..7 : per-group arrival counters (256B apart), group = wg&7
//   bar[600]          : global group counter
//   bar[768]          : generation (total completed barriers this launch)
// All counter ops RELAXED; one release fence before arrival, one acquire fence
// after wake. Counters monotonic (mod tests) -> no reset-ordering hazard.
// Spin compares gen against caller-supplied target; stale reads only delay.
__device__ __forceinline__ void grid_barrier(unsigned int* bar, unsigned int target) {
  __syncthreads();
  if (threadIdx.x == 0) {
    __builtin_amdgcn_fence(__ATOMIC_RELEASE, "agent");   // h stores -> device visible
    unsigned int* xcnt = bar + 64 * (blockIdx.x & 7);
    unsigned int* gcnt = bar + 600;
    unsigned int* gen  = bar + 768;
    unsigned int my = __hip_atomic_fetch_add(xcnt, 1u, __ATOMIC_RELAXED, __HIP_MEMORY_SCOPE_AGENT);
    if ((my & 31u) == 31u) {
      unsigned int mg = __hip_atomic_fetch_add(gcnt, 1u, __ATOMIC_RELAXED, __HIP_MEMORY_SCOPE_AGENT);
      if ((mg & 7u) == 7u) {
        __hip_atomic_fetch_add(gen, 1u, __ATOMIC_RELAXED, __HIP_MEMORY_SCOPE_AGENT);
      }
    }
    for (unsigned int it = 0; it < (1u << 14); ++it) {
      unsigned int g = __hip_atomic_load(gen, __ATOMIC_RELAXED, __HIP_MEMORY_SCOPE_AGENT);
      if ((int)(g - target) >= 0) break;
      __builtin_amdgcn_s_sleep(2);
    }
    __builtin_amdgcn_fence(__ATOMIC_ACQUIRE, "agent");   // invalidate L1/L2 before h reads
  }
  __syncthreads();
}

// --------------------------- gemm_bt: C = A @ B^T ---------------------------
// A: (M,K) bf16 row-major. B: (4096,K) bf16.
// Output alt layout xw[(t_local*4096 + n)*256 + b], m = t_local*256 + b.
__global__ __launch_bounds__(256) void gemm_bt_xw(
    const unsigned short* __restrict__ A,
    const unsigned short* __restrict__ B,
    unsigned short* __restrict__ xw,
    int K)
{
  const int tid = threadIdx.x, lane = tid & 63, w = tid >> 6;
  const int m0 = blockIdx.x * 128;
  const int n0 = blockIdx.y * 128;
  __shared__ unsigned short As[128 * 64];
  __shared__ unsigned short Bs[128 * 64];
  const int mrow0 = (w & 1) * 64, ncol0 = (w >> 1) * 64;
  const int quad = lane >> 4;

  f32x4 acc[4][4];
  #pragma unroll
  for (int i = 0; i < 4; ++i)
    #pragma unroll
    for (int j = 0; j < 4; ++j) acc[i][j] = f32x4{0.f, 0.f, 0.f, 0.f};

  const int kiter = K >> 6;
  for (int ki = 0; ki < kiter; ++ki) {
    const int k0 = ki * 64;
    __syncthreads();
    #pragma unroll
    for (int i = 0; i < 4; ++i) {
      int G = i * 256 + tid;
      int row = G >> 3, c8 = (G & 7) * 8;
      uint4v va = *(const uint4v*)(A + (size_t)(m0 + row) * K + k0 + c8);
      uint4v vb = *(const uint4v*)(B + (size_t)(n0 + row) * K + k0 + c8);
      *(uint4v*)(As + row * 64 + c8) = va;
      *(uint4v*)(Bs + row * 64 + c8) = vb;
    }
    __syncthreads();
    #pragma unroll
    for (int kk = 0; kk < 2; ++kk) {
      bf16x8 af[4], bfr[4];
      #pragma unroll
      for (int mt = 0; mt < 4; ++mt)
        af[mt] = *(const bf16x8*)(As + (mrow0 + mt * 16 + (lane & 15)) * 64 + kk * 32 + quad * 8);
      #pragma unroll
      for (int nt = 0; nt < 4; ++nt)
        bfr[nt] = *(const bf16x8*)(Bs + (ncol0 + nt * 16 + (lane & 15)) * 64 + kk * 32 + quad * 8);
      #pragma unroll
      for (int mt = 0; mt < 4; ++mt)
        #pragma unroll
        for (int nt = 0; nt < 4; ++nt)
          acc[mt][nt] = __builtin_amdgcn_mfma_f32_16x16x32_bf16(af[mt], bfr[nt], acc[mt][nt], 0, 0, 0);
    }
  }
  #pragma unroll
  for (int mt = 0; mt < 4; ++mt) {
    int m = m0 + mrow0 + mt * 16 + quad * 4;
    int tl = m >> 8, b = m & 255;
    #pragma unroll
    for (int nt = 0; nt < 4; ++nt) {
      int col = n0 + ncol0 + nt * 16 + (lane & 15);
      ushort4v v;
      v.x = f2bf(acc[mt][nt][0]); v.y = f2bf(acc[mt][nt][1]);
      v.z = f2bf(acc[mt][nt][2]); v.w = f2bf(acc[mt][nt][3]);
      *(ushort4v*)(xw + ((size_t)tl * GDIM + col) * BATCH + b) = v;
    }
  }
}

// --------------------------- layer 0: fused persistent chunk -----------------
__global__ __launch_bounds__(256, 1) void lstm_layer0_kernel(
    const unsigned short* __restrict__ xbf,  // (T,B,F) bf16
    const float* __restrict__ Wih,           // (4096,128) fp32
    const float* __restrict__ Whh,           // (4096,1024) fp32
    const float* __restrict__ bih,
    const float* __restrict__ bhh,
    unsigned short* __restrict__ slab,       // (ch_len+1, B, H) bf16
    float* __restrict__ cstate,              // (B,H) fp32
    int t0, int ch_len, unsigned int gen_base,
    float* __restrict__ dout_h,
    float* __restrict__ dout_c,
    unsigned int* __restrict__ bar)
{
  const int tid = threadIdx.x, lane = tid & 63, wv = tid >> 6;
  const int quad = lane >> 4;
  const int wg = blockIdx.x;
  const int mi = wg & 7, ni = wg >> 3;
  const int r0 = mi * 32, hc0 = ni * 32;

  __shared__ unsigned short As[32 * (AS_STRIDE / 2)];
  __shared__ float gbuf[4][32][36];

  bf16x8 whh[2][32];
  #pragma unroll
  for (int nt = 0; nt < 2; ++nt) {
    const float* wrow = Whh + (size_t)(wv * HDIM + hc0 + nt * 16 + (lane & 15)) * HDIM + quad * 8;
    #pragma unroll
    for (int kk = 0; kk < 32; ++kk) {
      f32x4 f0 = *(const f32x4*)(wrow + kk * 32);
      f32x4 f1 = *(const f32x4*)(wrow + kk * 32 + 4);
      bf16x8 r;
      r[0] = (__bf16)f0[0]; r[1] = (__bf16)f0[1]; r[2] = (__bf16)f0[2]; r[3] = (__bf16)f0[3];
      r[4] = (__bf16)f1[0]; r[5] = (__bf16)f1[1]; r[6] = (__bf16)f1[2]; r[7] = (__bf16)f1[3];
      whh[nt][kk] = r;
    }
  }
  bf16x8 wih[2][4];
  #pragma unroll
  for (int nt = 0; nt < 2; ++nt) {
    const float* wrow = Wih + (size_t)(wv * HDIM + hc0 + nt * 16 + (lane & 15)) * FDIM + quad * 8;
    #pragma unroll
    for (int kk = 0; kk < 4; ++kk) {
      f32x4 f0 = *(const f32x4*)(wrow + kk * 32);
      f32x4 f1 = *(const f32x4*)(wrow + kk * 32 + 4);
      bf16x8 r;
      r[0] = (__bf16)f0[0]; r[1] = (__bf16)f0[1]; r[2] = (__bf16)f0[2]; r[3] = (__bf16)f0[3];
      r[4] = (__bf16)f1[0]; r[5] = (__bf16)f1[1]; r[6] = (__bf16)f1[2]; r[7] = (__bf16)f1[3];
      wih[nt][kk] = r;
    }
  }

  const int hcl = tid & 31, rg = tid >> 5;
  float bias[4];
  #pragma unroll
  for (int g = 0; g < 4; ++g)
    bias[g] = bih[g * HDIM + hc0 + hcl] + bhh[g * HDIM + hc0 + hcl];

  float c[4];
  #pragma unroll
  for (int r = 0; r < 4; ++r)
    c[r] = (t0 == 0) ? 0.f : cstate[(size_t)(r0 + rg * 4 + r) * HDIM + hc0 + hcl];

  const int tend = t0 + ch_len;
  #pragma unroll 1
  for (int t = t0; t < tend; ++t) {
    f32x4 acc[2][2];
    #pragma unroll
    for (int mt = 0; mt < 2; ++mt)
      #pragma unroll
      for (int nt = 0; nt < 2; ++nt) acc[mt][nt] = f32x4{0.f, 0.f, 0.f, 0.f};

    // x projection (K=128), independent of h
    #pragma unroll
    for (int j = 0; j < 4; ++j) {
      bf16x8 af[2];
      #pragma unroll
      for (int mt = 0; mt < 2; ++mt)
        af[mt] = *(const bf16x8*)(xbf + (size_t)(t * BATCH + r0 + mt * 16 + (lane & 15)) * FDIM + j * 32 + quad * 8);
      #pragma unroll
      for (int mt = 0; mt < 2; ++mt)
        #pragma unroll
        for (int nt = 0; nt < 2; ++nt)
          acc[mt][nt] = __builtin_amdgcn_mfma_f32_16x16x32_bf16(af[mt], wih[nt][j], acc[mt][nt], 0, 0, 0);
    }

    if (t > 0) {
      const unsigned short* Aprev = slab + (size_t)(t - t0) * (BATCH * HDIM);
      #pragma unroll
      for (int p = 0; p < 16; ++p) {
        int idx = p * 256 + tid;
        int row = idx >> 7, gc = idx & 127;
        *(uint4v*)((char*)As + row * AS_STRIDE + gc * 16) =
            *(const uint4v*)(Aprev + (size_t)(r0 + row) * HDIM + gc * 8);
      }
      __syncthreads();
      #pragma unroll
      for (int j = 0; j < 32; ++j) {
        bf16x8 af[2];
        #pragma unroll
        for (int mt = 0; mt < 2; ++mt)
          af[mt] = *(const bf16x8*)((const char*)As + (mt * 16 + (lane & 15)) * AS_STRIDE + j * 64 + quad * 16);
        #pragma unroll
        for (int mt = 0; mt < 2; ++mt)
          #pragma unroll
          for (int nt = 0; nt < 2; ++nt)
            acc[mt][nt] = __builtin_amdgcn_mfma_f32_16x16x32_bf16(af[mt], whh[nt][j], acc[mt][nt], 0, 0, 0);
      }
    }

    __syncthreads();
    #pragma unroll
    for (int mt = 0; mt < 2; ++mt)
      #pragma unroll
      for (int nt = 0; nt < 2; ++nt) {
        int hl = nt * 16 + (lane & 15);
        int rq = mt * 16 + quad * 4;
        *(f32x4*)&gbuf[wv][hl][rq] = acc[mt][nt];
      }
    __syncthreads();

    unsigned short* hdst = slab + (size_t)(t - t0 + 1) * (BATCH * HDIM);
    unsigned short* hdst0 = slab;
    #pragma unroll
    for (int r = 0; r < 4; ++r) {
      int row = rg * 4 + r;
      float gi = gbuf[0][hcl][row] + bias[0];
      float gf = gbuf[1][hcl][row] + bias[1];
      float gg = gbuf[2][hcl][row] + bias[2];
      float go = gbuf[3][hcl][row] + bias[3];
      float iv = sigm(gi), fv = sigm(gf), gv = tanh_f(gg), ov = sigm(go);
      float cn = fv * c[r] + iv * gv;
      c[r] = cn;
      float hv = ov * tanh_f(cn);
      int gidx = (r0 + row) * HDIM + hc0 + hcl;
      unsigned short hb = f2bf(hv);
      hdst[gidx] = hb;
      if (t == tend - 1) { hdst0[gidx] = hb; cstate[gidx] = cn; }
      if (t == T_STEPS - 1) { dout_h[gidx] = hv; dout_c[gidx] = cn; }
    }

    if (t != tend - 1) grid_barrier(bar, gen_base + (unsigned int)(t - t0) + 1u);
  }
}

// --------------------------- layer 1: persistent chunk ----------------------
__global__ __launch_bounds__(256, 1) void lstm_layer1_kernel(
    const unsigned short* __restrict__ xw,   // (ch_len, 4096, 256) bf16
    const float* __restrict__ Whh,
    const float* __restrict__ bih,
    const float* __restrict__ bhh,
    unsigned short* __restrict__ hpp,        // 2-slot ping-pong
    float* __restrict__ cstate,
    int t0, int ch_len, unsigned int gen_base,
    unsigned short* __restrict__ h1t0,
    float* __restrict__ dout_h,
    float* __restrict__ dout_c,
    unsigned int* __restrict__ bar)
{
  const int tid = threadIdx.x, lane = tid & 63, wv = tid >> 6;
  const int quad = lane >> 4;
  const int wg = blockIdx.x;
  const int mi = wg & 7, ni = wg >> 3;
  const int r0 = mi * 32, hc0 = ni * 32;

  __shared__ unsigned short As[32 * (AS_STRIDE / 2)];
  __shared__ float gbuf[4][32][36];

  bf16x8 whh[2][32];
  #pragma unroll
  for (int nt = 0; nt < 2; ++nt) {
    const float* wrow = Whh + (size_t)(wv * HDIM + hc0 + nt * 16 + (lane & 15)) * HDIM + quad * 8;
    #pragma unroll
    for (int kk = 0; kk < 32; ++kk) {
      f32x4 f0 = *(const f32x4*)(wrow + kk * 32);
      f32x4 f1 = *(const f32x4*)(wrow + kk * 32 + 4);
      bf16x8 r;
      r[0] = (__bf16)f0[0]; r[1] = (__bf16)f0[1]; r[2] = (__bf16)f0[2]; r[3] = (__bf16)f0[3];
      r[4] = (__bf16)f1[0]; r[5] = (__bf16)f1[1]; r[6] = (__bf16)f1[2]; r[7] = (__bf16)f1[3];
      whh[nt][kk] = r;
    }
  }

  const int hcl = tid & 31, rg = tid >> 5;
  float bias[4];
  #pragma unroll
  for (int g = 0; g < 4; ++g)
    bias[g] = bih[g * HDIM + hc0 + hcl] + bhh[g * HDIM + hc0 + hcl];

  float c[4];
  #pragma unroll
  for (int r = 0; r < 4; ++r)
    c[r] = (t0 == 0) ? 0.f : cstate[(size_t)(r0 + rg * 4 + r) * HDIM + hc0 + hcl];

  const int tend = t0 + ch_len;
  #pragma unroll 1
  for (int t = t0; t < tend; ++t) {
    // hoist xw loads (independent of h) to overlap LLC latency with h-GEMM
    float xwv[4][4];
    #pragma unroll
    for (int g = 0; g < 4; ++g) {
      const unsigned short* xp =
          xw + ((size_t)(t - t0) * GDIM + g * HDIM + hc0 + hcl) * BATCH + r0 + rg * 4;
      ushort4v u = *(const ushort4v*)xp;
      xwv[g][0] = bf2f(u.x); xwv[g][1] = bf2f(u.y);
      xwv[g][2] = bf2f(u.z); xwv[g][3] = bf2f(u.w);
    }

    f32x4 acc[2][2];
    #pragma unroll
    for (int mt = 0; mt < 2; ++mt)
      #pragma unroll
      for (int nt = 0; nt < 2; ++nt) acc[mt][nt] = f32x4{0.f, 0.f, 0.f, 0.f};

    if (t > 0) {
      const unsigned short* Aprev = hpp + (size_t)((t - 1) & 1) * (BATCH * HDIM);
      #pragma unroll
      for (int p = 0; p < 16; ++p) {
        int idx = p * 256 + tid;
        int row = idx >> 7, gc = idx & 127;
        *(uint4v*)((char*)As + row * AS_STRIDE + gc * 16) =
            *(const uint4v*)(Aprev + (size_t)(r0 + row) * HDIM + gc * 8);
      }
      __syncthreads();
      #pragma unroll
      for (int j = 0; j < 32; ++j) {
        bf16x8 af[2];
        #pragma unroll
        for (int mt = 0; mt < 2; ++mt)
          af[mt] = *(const bf16x8*)((const char*)As + (mt * 16 + (lane & 15)) * AS_STRIDE + j * 64 + quad * 16);
        #pragma unroll
        for (int mt = 0; mt < 2; ++mt)
          #pragma unroll
          for (int nt = 0; nt < 2; ++nt)
            acc[mt][nt] = __builtin_amdgcn_mfma_f32_16x16x32_bf16(af[mt], whh[nt][j], acc[mt][nt], 0, 0, 0);
      }
    }

    __syncthreads();
    #pragma unroll
    for (int mt = 0; mt < 2; ++mt)
      #pragma unroll
      for (int nt = 0; nt < 2; ++nt) {
        int hl = nt * 16 + (lane & 15);
        int rq = mt * 16 + quad * 4;
        *(f32x4*)&gbuf[wv][hl][rq] = acc[mt][nt];
      }
    __syncthreads();

    unsigned short* hdst = hpp + (size_t)(t & 1) * (BATCH * HDIM);
    #pragma unroll
    for (int r = 0; r < 4; ++r) {
      int row = rg * 4 + r;
      float gi = gbuf[0][hcl][row] + xwv[0][r] + bias[0];
      float gf = gbuf[1][hcl][row] + xwv[1][r] + bias[1];
      float gg = gbuf[2][hcl][row] + xwv[2][r] + bias[2];
      float go = gbuf[3][hcl][row] + xwv[3][r] + bias[3];
      float iv = sigm(gi), fv = sigm(gf), gv = tanh_f(gg), ov = sigm(go);
      float cn = fv * c[r] + iv * gv;
      c[r] = cn;
      float hv = ov * tanh_f(cn);
      int gidx = (r0 + row) * HDIM + hc0 + hcl;
      hdst[gidx] = f2bf(hv);
      if (h1t0 != nullptr && t == 0) h1t0[gidx] = f2bf(hv);
      if (t == tend - 1) cstate[gidx] = cn;
      if (t == T_STEPS - 1) { dout_h[gidx] = hv; dout_c[gidx] = cn; }
    }

    if (t != tend - 1) grid_barrier(bar, gen_base + (unsigned int)(t - t0) + 1u);
  }
}

__global__ void y_kernel(const unsigned short* __restrict__ h1t0,
                         const unsigned short* __restrict__ wlin,
                         const float* __restrict__ blin,
                         float* __restrict__ y)
{
  int b = blockIdx.x;
  int f = threadIdx.x;
  const ushort8v* hp = (const ushort8v*)(h1t0 + (size_t)b * HDIM);
  const ushort8v* wp = (const ushort8v*)(wlin + (size_t)f * HDIM);
  float acc = 0.f;
  for (int i = 0; i < HDIM / 8; ++i) {
    ushort8v hv = hp[i], wvv = wp[i];
    #pragma unroll
    for (int j = 0; j < 8; ++j) acc += bf2f(hv[j]) * bf2f(wvv[j]);
  }
  y[b * FDIM + f] = acc + blin[f];
}

// ---------------------------------------------------------------------------
extern "C" void kernel_launch(void* const* d_in, const int* in_sizes, int n_in,
                              void* d_out, int out_size, void* d_ws, size_t ws_size,
                              hipStream_t stream) {
  (void)in_sizes; (void)n_in; (void)out_size;
  const float* x    = (const float*)d_in[0];
  const float* Wih0 = (const float*)d_in[1];
  const float* Whh0 = (const float*)d_in[2];
  const float* bih0 = (const float*)d_in[3];
  const float* bhh0 = (const float*)d_in[4];
  const float* Wih1 = (const float*)d_in[5];
  const float* Whh1 = (const float*)d_in[6];
  const float* bih1 = (const float*)d_in[7];
  const float* bhh1 = (const float*)d_in[8];
  const float* Wlin = (const float*)d_in[9];
  const float* blin = (const float*)d_in[10];
  float* out = (float*)d_out;

  const size_t SZ_BAR   = 16384;
  const size_t SZ_XBF   = (size_t)T_STEPS * BATCH * FDIM * 2;
  const size_t SZ_WIH1  = (size_t)GDIM * HDIM * 2;
  const size_t SZ_WLIN  = (size_t)FDIM * HDIM * 2;
  const size_t SZ_HPP   = (size_t)2 * BATCH * HDIM * 2;
  const size_t SZ_H1T0  = (size_t)BATCH * HDIM * 2;
  const size_t SZ_CST   = (size_t)BATCH * HDIM * 4;
  const size_t SLOT     = (size_t)BATCH * HDIM * 2;
  const size_t fixed = SZ_BAR + SZ_XBF + SZ_WIH1 + SZ_WLIN + SZ_HPP + SZ_H1T0 + 2 * SZ_CST;

  int CH = 0;
  const int cands[5] = {64, 32, 16, 8, 4};
  for (int i = 0; i < 5; ++i) {
    int c = cands[i];
    size_t need = fixed + (size_t)(c + 1) * SLOT + (size_t)c * GDIM * BATCH * 2;
    if (need <= ws_size) { CH = c; break; }
  }
  if (CH == 0) {
    float v = 1.0e6f + (float)(ws_size >> 20);
    diag_kernel<<<(32768 + 255) / 256, 256, 0, stream>>>(out, 32768, v);
    return;
  }

  char* ws = (char*)d_ws;
  size_t o = 0;
  unsigned int*   bar   = (unsigned int*)(ws + o);    o += SZ_BAR;
  unsigned short* xbf   = (unsigned short*)(ws + o);  o += SZ_XBF;
  unsigned short* wih1b = (unsigned short*)(ws + o);  o += SZ_WIH1;
  unsigned short* wlinb = (unsigned short*)(ws + o);  o += SZ_WLIN;
  unsigned short* h1pp  = (unsigned short*)(ws + o);  o += SZ_HPP;
  unsigned short* h1t0  = (unsigned short*)(ws + o);  o += SZ_H1T0;
  float*          c0st  = (float*)(ws + o);           o += SZ_CST;
  float*          c1st  = (float*)(ws + o);           o += SZ_CST;
  unsigned short* slab  = (unsigned short*)(ws + o);  o += (size_t)(CH + 1) * SLOT;
  unsigned short* xw1   = (unsigned short*)(ws + o);  o += (size_t)CH * GDIM * BATCH * 2;

  hipMemsetAsync(bar, 0, SZ_BAR, stream);

  conv_bf16<<<(T_STEPS * BATCH * FDIM + 255) / 256, 256, 0, stream>>>(x, xbf, T_STEPS * BATCH * FDIM);
  conv_bf16<<<(GDIM * HDIM + 255) / 256, 256, 0, stream>>>(Wih1, wih1b, GDIM * HDIM);
  conv_bf16<<<(FDIM * HDIM + 255) / 256, 256, 0, stream>>>(Wlin, wlinb, FDIM * HDIM);

  float* hn0 = out + 32768;
  float* hn1 = out + 32768 + 262144;
  float* cn0 = out + 32768 + 524288;
  float* cn1 = out + 32768 + 524288 + 262144;

  unsigned int gen_base = 0;
  for (int ch = 0; ch < T_STEPS / CH; ++ch) {
    int t0 = ch * CH;
    lstm_layer0_kernel<<<256, 256, 0, stream>>>(
        xbf, Wih0, Whh0, bih0, bhh0, slab, c0st, t0, CH, gen_base, hn0, cn0, bar);
    gen_base += (unsigned int)(CH - 1);
    gemm_bt_xw<<<dim3(CH * 2, 32), 256, 0, stream>>>(
        slab + BATCH * HDIM, wih1b, xw1, HDIM);
    lstm_layer1_kernel<<<256, 256, 0, stream>>>(
        xw1, Whh1, bih1, bhh1, h1pp, c1st, t0, CH, gen_base, h1t0, hn1, cn1, bar);
    gen_base += (unsigned int)(CH - 1);
  }

  y_kernel<<<256, 128, 0, stream>>>(h1t0, wlinb, blin, out);
}